// Round 3
// baseline (1838.521 us; speedup 1.0000x reference)
//
#include <hip/hip_runtime.h>
#include <hip/hip_bf16.h>

typedef _Float16 half8_t __attribute__((ext_vector_type(8)));
typedef _Float16 half4_t __attribute__((ext_vector_type(4)));
typedef float float4_t __attribute__((ext_vector_type(4)));

#define TT 1024
#define BB 128
#define EE 128
#define HH 128
#define NTAG 64
#define ASTR 144  // LDS row stride (f16): 288 B/row, 16B-aligned fragments

__device__ __forceinline__ float fast_sigmoid(float x) {
  return __builtin_amdgcn_rcpf(1.0f + __builtin_amdgcn_exp2f(-1.44269504088896f * x));
}
__device__ __forceinline__ float fast_tanh(float x) {
  return 1.0f - 2.0f * __builtin_amdgcn_rcpf(1.0f + __builtin_amdgcn_exp2f(2.88539008177793f * x));
}
__device__ __forceinline__ float fast_exp(float x) {
  return __builtin_amdgcn_exp2f(x * 1.44269504088896f);
}

// ---------------------------------------------------------------- init: zero LSTM state (196,608 B)
__global__ __launch_bounds__(256) void init_kernel(float4_t* __restrict__ p) {
  p[blockIdx.x * 256 + threadIdx.x] = (float4_t){0.f, 0.f, 0.f, 0.f};
}

// ---------------------------------------------------------------- embed: x[t,b,:] = f16(emb[kmers[t,b]])
__global__ __launch_bounds__(256) void embed_kernel(const int* __restrict__ kmers,
                                                    const float* __restrict__ emb,
                                                    half4_t* __restrict__ x) {
  const int g = blockIdx.x * 256 + threadIdx.x;  // T*B*32 threads
  const int row = g >> 5, seg = g & 31;
  const int km = kmers[row];
  const float4_t v = ((const float4_t*)(emb + (size_t)km * EE))[seg];
  half4_t o;
  o[0] = (_Float16)v[0]; o[1] = (_Float16)v[1];
  o[2] = (_Float16)v[2]; o[3] = (_Float16)v[3];
  x[(size_t)row * 32 + seg] = o;
}

// ---------------------------------------------------------------- xg segment: gates for Tseg steps, one dir per block
// Block bb (within dir) covers i_loc in {2bb, 2bb+1}; 16 m-tiles (2 i_loc x 8 chunks).
// Layout (per dir, stride Tseg*65536 elems): [(i_loc*8+chunk)*8 + wj][gj][lane*4+r] f16.
__global__ __launch_bounds__(1024, 1) void xg_kernel(
    const _Float16* __restrict__ x,
    const float* __restrict__ w_ih_f, const float* __restrict__ b_ih_f, const float* __restrict__ b_hh_f,
    const float* __restrict__ w_ih_b, const float* __restrict__ b_ih_b, const float* __restrict__ b_hh_b,
    _Float16* __restrict__ xgbuf, int s, int Tseg) {
  __shared__ _Float16 As[2][16 * ASTR];
  const int tid = threadIdx.x;
  const int wave = tid >> 6, lane = tid & 63;
  const int n16 = lane & 15, quad = lane >> 4;
  const int nblk = Tseg >> 1;
  const int dir = (blockIdx.x >= nblk) ? 1 : 0;
  const int bb = dir ? (blockIdx.x - nblk) : blockIdx.x;

  const float* wih = dir ? w_ih_b : w_ih_f;
  const float* bih = dir ? b_ih_b : b_ih_f;
  const float* bhh = dir ? b_hh_b : b_hh_f;

  half8_t bf[2][4];  // [j][kf]
  float bias[2];
  int gj[2], wj[2];
#pragma unroll
  for (int j = 0; j < 2; ++j) {
    const int nf = wave * 2 + j;  // 0..31 n-tiles (4 gates x 8 hu-tiles)
    gj[j] = nf >> 3; wj[j] = nf & 7;
    const int row = gj[j] * HH + wj[j] * 16 + n16;
    bias[j] = bih[row] + bhh[row];
#pragma unroll
    for (int kf = 0; kf < 4; ++kf) {
      const float* src = wih + row * EE + kf * 32 + quad * 8;
#pragma unroll
      for (int i = 0; i < 8; ++i) bf[j][kf][i] = (_Float16)src[i];
    }
  }
  const int sr = tid >> 4, scb = tid & 15;
#define MTG(mi) (((dir) ? (TT - 1 - s * Tseg - (2 * bb + ((mi) >> 3))) : (s * Tseg + (2 * bb + ((mi) >> 3)))) * 8 + ((mi) & 7))
  if (tid < 256)
    *(half8_t*)(&As[0][sr * ASTR + scb * 8]) =
        *(const half8_t*)(x + ((size_t)MTG(0) * 16 + sr) * 128 + scb * 8);
  __syncthreads();
  for (int mi = 0; mi < 16; ++mi) {
    half8_t stg = {};
    if (tid < 256 && mi < 15)
      stg = *(const half8_t*)(x + ((size_t)MTG(mi + 1) * 16 + sr) * 128 + scb * 8);
    const _Float16* Ab = &As[mi & 1][0];
    half8_t af[4];
#pragma unroll
    for (int kf = 0; kf < 4; ++kf) af[kf] = *(const half8_t*)(Ab + n16 * ASTR + kf * 32 + quad * 8);
    float4_t acc[2];
#pragma unroll
    for (int j = 0; j < 2; ++j) acc[j] = (float4_t){bias[j], bias[j], bias[j], bias[j]};
#pragma unroll
    for (int kf = 0; kf < 4; ++kf)
#pragma unroll
      for (int j = 0; j < 2; ++j)
        acc[j] = __builtin_amdgcn_mfma_f32_16x16x32_f16(af[kf], bf[j][kf], acc[j], 0, 0, 0);
    const int mtl = (2 * bb + (mi >> 3)) * 8 + (mi & 7);
#pragma unroll
    for (int j = 0; j < 2; ++j) {
      half4_t o;
#pragma unroll
      for (int r = 0; r < 4; ++r) o[r] = (_Float16)acc[j][r];
      *(half4_t*)(xgbuf + (size_t)dir * Tseg * 65536 +
                  (((size_t)mtl * 8 + wj[j]) * 4 + gj[j]) * 256 + lane * 4) = o;
    }
    if (tid < 256 && mi < 15)
      *(half8_t*)(&As[(mi + 1) & 1][sr * ASTR + scb * 8]) = stg;
    __syncthreads();
  }
#undef MTG
}

// ---------------------------------------------------------------- bidirectional LSTM segment (recurrence only)
// grid 16: wg = dir*8 + chunk, 16 batches each, Tseg steps. Gates = xg + h@W_hh (K=128).
__global__ __launch_bounds__(512, 2) void lstm_kernel(
    const _Float16* __restrict__ xgbuf,
    const float* __restrict__ w_hh_f, const float* __restrict__ w_hh_b,
    _Float16* __restrict__ h_cat, _Float16* __restrict__ h_state, float* __restrict__ c_state,
    int s, int Tseg) {
  __shared__ _Float16 A[2][16 * ASTR];
  const int wg = blockIdx.x;
  const int dir = wg >> 3, chunk = wg & 7;
  const int b0 = chunk * 16;
  const float* w_hh = dir ? w_hh_b : w_hh_f;
  const int tid = threadIdx.x;
  const int wave = tid >> 6, lane = tid & 63;
  const int n16 = lane & 15, quad = lane >> 4;
  const int hu = wave * 16 + n16;

  half8_t bf[4][4];  // [gate][kf] of W_hh (K=128)
#pragma unroll
  for (int g = 0; g < 4; ++g) {
    const int ng = g * HH + hu;
#pragma unroll
    for (int kf = 0; kf < 4; ++kf) {
      const float* src = w_hh + ng * HH + kf * 32 + quad * 8;
#pragma unroll
      for (int i = 0; i < 8; ++i) bf[g][kf][i] = (_Float16)src[i];
    }
  }
  // load persistent state (fragment order: per-lane 4 rows quad*4+r at col hu)
  const int sidx = ((wg * 8 + wave) * 64 + lane) * 4;
  half4_t h4 = *(const half4_t*)(h_state + sidx);
  float4_t c4 = *(const float4_t*)(c_state + sidx);
  float c[4] = {c4[0], c4[1], c4[2], c4[3]};
#pragma unroll
  for (int r = 0; r < 4; ++r) A[0][(quad * 4 + r) * ASTR + hu] = h4[r];

  const _Float16* xgw = xgbuf + (size_t)dir * Tseg * 65536 + (chunk * 8 + wave) * 1024 + lane * 4;
  half4_t xv[4];
#pragma unroll
  for (int g = 0; g < 4; ++g) xv[g] = *(const half4_t*)(xgw + g * 256);
  half4_t hlast = h4;
  __syncthreads();

  for (int il = 0; il < Tseg; ++il) {
    half4_t xn[4] = {};
    if (il + 1 < Tseg) {
#pragma unroll
      for (int g = 0; g < 4; ++g)
        xn[g] = *(const half4_t*)(xgw + (size_t)(il + 1) * 65536 + g * 256);
    }
    __syncthreads();  // h_{i-1} in buf[il&1] ready
    const _Float16* Ab = &A[il & 1][0];
    _Float16* An = &A[(il + 1) & 1][0];
    half8_t af[4];
#pragma unroll
    for (int kf = 0; kf < 4; ++kf) af[kf] = *(const half8_t*)(Ab + n16 * ASTR + kf * 32 + quad * 8);
    float4_t acc[4];
#pragma unroll
    for (int g = 0; g < 4; ++g)
      acc[g] = (float4_t){(float)xv[g][0], (float)xv[g][1], (float)xv[g][2], (float)xv[g][3]};
#pragma unroll
    for (int kf = 0; kf < 4; ++kf)
#pragma unroll
      for (int g = 0; g < 4; ++g)
        acc[g] = __builtin_amdgcn_mfma_f32_16x16x32_f16(af[kf], bf[g][kf], acc[g], 0, 0, 0);
#pragma unroll
    for (int g = 0; g < 4; ++g) xv[g] = xn[g];
    const int i = s * Tseg + il;
    const int te = dir ? (TT - 1 - i) : i;
    _Float16* gptr = h_cat + ((size_t)te * BB + b0 + quad * 4) * 256 + dir * HH + hu;
#pragma unroll
    for (int r = 0; r < 4; ++r) {
      const float gi = acc[0][r], gf = acc[1][r], gg = acc[2][r], go = acc[3][r];
      const float cr = fast_sigmoid(gf) * c[r] + fast_sigmoid(gi) * fast_tanh(gg);
      c[r] = cr;
      const float hv = fast_sigmoid(go) * fast_tanh(cr);
      const _Float16 hh = (_Float16)hv;
      An[(quad * 4 + r) * ASTR + hu] = hh;  // h_i for next step
      gptr[r * 256] = hh;                   // h_cat[te][b][dir*128+hu]
      hlast[r] = hh;
    }
  }
  // persist state for next segment
  *(half4_t*)(h_state + sidx) = hlast;
  c4[0] = c[0]; c4[1] = c[1]; c4[2] = c[2]; c4[3] = c[3];
  *(float4_t*)(c_state + sidx) = c4;
}

// ---------------------------------------------------------------- emissions: em = h_cat @ w_proj^T + b_proj
__global__ __launch_bounds__(256) void emis_kernel(const _Float16* __restrict__ h_cat,
                                                   const float* __restrict__ w_proj,
                                                   const float* __restrict__ b_proj,
                                                   float* __restrict__ em) {
  const int tid = threadIdx.x;
  const int wave = tid >> 6, lane = tid & 63;
  const int n16 = lane & 15, quad = lane >> 4;
  const size_t row0 = (size_t)blockIdx.x * 64 + wave * 16;

  half8_t bf[4][8];
#pragma unroll
  for (int nt = 0; nt < 4; ++nt) {
    const float* wp = w_proj + (nt * 16 + n16) * 256;
#pragma unroll
    for (int kf = 0; kf < 8; ++kf) {
      const int kb = kf * 32 + quad * 8;
#pragma unroll
      for (int i = 0; i < 8; ++i) bf[nt][kf][i] = (_Float16)wp[kb + i];
    }
  }
  float4_t acc[4];
#pragma unroll
  for (int nt = 0; nt < 4; ++nt) {
    const float bv = b_proj[nt * 16 + n16];
    acc[nt] = (float4_t){bv, bv, bv, bv};
  }
#pragma unroll
  for (int kf = 0; kf < 8; ++kf) {
    half8_t af = *(const half8_t*)(h_cat + (row0 + n16) * 256 + kf * 32 + quad * 8);
#pragma unroll
    for (int nt = 0; nt < 4; ++nt)
      acc[nt] = __builtin_amdgcn_mfma_f32_16x16x32_f16(af, bf[nt][kf], acc[nt], 0, 0, 0);
  }
#pragma unroll
  for (int nt = 0; nt < 4; ++nt)
#pragma unroll
    for (int r = 0; r < 4; ++r)
      em[(row0 + quad * 4 + r) * NTAG + nt * 16 + n16] = acc[nt][r];
}

// ---------------------------------------------------------------- CRF forward, wave-autonomous
// 1 wave per wg, 4 batches (b=n16&3, duplicated over n16 groups). State in A-frag layout regs.
__global__ __launch_bounds__(64) void crf_kernel(const float* __restrict__ em,
                                                 const float* __restrict__ trans,
                                                 const float* __restrict__ start_trans,
                                                 const float* __restrict__ end_trans,
                                                 float* __restrict__ denom) {
  __shared__ float tmp[4 * 68];  // rows 272 B apart -> 16B-aligned float4 views
  const int lane = threadIdx.x;
  const int n16 = lane & 15, quad = lane >> 4;
  const int b = n16 & 3;
  const int gb = blockIdx.x * 4 + b;

  half8_t ef[4][2];  // exp(trans) B-frags [nt][kf]
#pragma unroll
  for (int nt = 0; nt < 4; ++nt)
#pragma unroll
    for (int kf = 0; kf < 2; ++kf)
#pragma unroll
      for (int i = 0; i < 8; ++i)
        ef[nt][kf][i] = (_Float16)fast_exp(trans[(kf * 32 + quad * 8 + i) * NTAG + nt * 16 + n16]);

  float sv[16], et[16];
#pragma unroll
  for (int kf = 0; kf < 2; ++kf) {
    const int j0 = kf * 32 + quad * 8;
    float4_t s0 = *(const float4_t*)(start_trans + j0);
    float4_t s1 = *(const float4_t*)(start_trans + j0 + 4);
    float4_t e0 = *(const float4_t*)(end_trans + j0);
    float4_t e1 = *(const float4_t*)(end_trans + j0 + 4);
    float4_t m0 = *(const float4_t*)(em + (size_t)gb * NTAG + j0);
    float4_t m1 = *(const float4_t*)(em + (size_t)gb * NTAG + j0 + 4);
#pragma unroll
    for (int i = 0; i < 4; ++i) {
      sv[kf * 8 + i] = s0[i] + m0[i];
      sv[kf * 8 + 4 + i] = s1[i] + m1[i];
      et[kf * 8 + i] = e0[i];
      et[kf * 8 + 4 + i] = e1[i];
    }
  }
  float4_t emn[4];
#pragma unroll
  for (int kf = 0; kf < 2; ++kf) {
    const size_t base = ((size_t)1 * BB + gb) * NTAG + kf * 32 + quad * 8;
    emn[kf * 2] = *(const float4_t*)(em + base);
    emn[kf * 2 + 1] = *(const float4_t*)(em + base + 4);
  }

  for (int t = 1; t < TT; ++t) {
    float4_t emc[4];
#pragma unroll
    for (int q = 0; q < 4; ++q) emc[q] = emn[q];
    if (t + 1 < TT) {
#pragma unroll
      for (int kf = 0; kf < 2; ++kf) {
        const size_t base = ((size_t)(t + 1) * BB + gb) * NTAG + kf * 32 + quad * 8;
        emn[kf * 2] = *(const float4_t*)(em + base);
        emn[kf * 2 + 1] = *(const float4_t*)(em + base + 4);
      }
    }
    float mx[8];
#pragma unroll
    for (int i = 0; i < 8; ++i) mx[i] = fmaxf(sv[i], sv[8 + i]);
#pragma unroll
    for (int i = 0; i < 4; ++i) mx[i] = fmaxf(mx[i], mx[4 + i]);
    float m = fmaxf(fmaxf(mx[0], mx[1]), fmaxf(mx[2], mx[3]));
    m = fmaxf(m, __shfl_xor(m, 16, 64));
    m = fmaxf(m, __shfl_xor(m, 32, 64));
    half8_t pa[2];
#pragma unroll
    for (int kf = 0; kf < 2; ++kf)
#pragma unroll
      for (int i = 0; i < 8; ++i)
        pa[kf][i] = (_Float16)__builtin_amdgcn_exp2f((sv[kf * 8 + i] - m) * 1.44269504088896f);
    float4_t acc[4];
#pragma unroll
    for (int nt = 0; nt < 4; ++nt) acc[nt] = (float4_t){0.f, 0.f, 0.f, 0.f};
#pragma unroll
    for (int kf = 0; kf < 2; ++kf)
#pragma unroll
      for (int nt = 0; nt < 4; ++nt)
        acc[nt] = __builtin_amdgcn_mfma_f32_16x16x32_f16(pa[kf], ef[nt][kf], acc[nt], 0, 0, 0);
    if (quad == 0) {
#pragma unroll
      for (int nt = 0; nt < 4; ++nt)
#pragma unroll
        for (int r = 0; r < 4; ++r) tmp[r * 68 + nt * 16 + n16] = acc[nt][r];
    }
    __syncthreads();
#pragma unroll
    for (int kf = 0; kf < 2; ++kf) {
      float4_t v0 = *(const float4_t*)(&tmp[b * 68 + kf * 32 + quad * 8]);
      float4_t v1 = *(const float4_t*)(&tmp[b * 68 + kf * 32 + quad * 8 + 4]);
#pragma unroll
      for (int i = 0; i < 4; ++i) {
        sv[kf * 8 + i] = m + 0.693147180559945f * __builtin_amdgcn_logf(v0[i]) + emc[kf * 2][i];
        sv[kf * 8 + 4 + i] = m + 0.693147180559945f * __builtin_amdgcn_logf(v1[i]) + emc[kf * 2 + 1][i];
      }
    }
    __syncthreads();
  }

#pragma unroll
  for (int i = 0; i < 16; ++i) sv[i] += et[i];
  float mx[8];
#pragma unroll
  for (int i = 0; i < 8; ++i) mx[i] = fmaxf(sv[i], sv[8 + i]);
#pragma unroll
  for (int i = 0; i < 4; ++i) mx[i] = fmaxf(mx[i], mx[4 + i]);
  float m = fmaxf(fmaxf(mx[0], mx[1]), fmaxf(mx[2], mx[3]));
  m = fmaxf(m, __shfl_xor(m, 16, 64));
  m = fmaxf(m, __shfl_xor(m, 32, 64));
  float s = 0.f;
#pragma unroll
  for (int i = 0; i < 16; ++i) s += fast_exp(sv[i] - m);
  s += __shfl_xor(s, 16, 64);
  s += __shfl_xor(s, 32, 64);
  if (lane < 4) denom[blockIdx.x * 4 + lane] = m + 0.693147180559945f * __builtin_amdgcn_logf(s);
}

// ---------------------------------------------------------------- numerator (tags constant over time)
__global__ __launch_bounds__(256) void numer_kernel(const float* __restrict__ em,
                                                    const int* __restrict__ tags,
                                                    const float* __restrict__ trans,
                                                    const float* __restrict__ start_trans,
                                                    const float* __restrict__ end_trans,
                                                    float* __restrict__ num) {
  const int b = blockIdx.x;
  const int tg = tags[b];
  float acc = 0.f;
  for (int t = threadIdx.x; t < TT; t += 256)
    acc += em[((size_t)t * BB + b) * NTAG + tg];
#pragma unroll
  for (int off = 32; off > 0; off >>= 1) acc += __shfl_xor(acc, off, 64);
  __shared__ float red[4];
  if ((threadIdx.x & 63) == 0) red[threadIdx.x >> 6] = acc;
  __syncthreads();
  if (threadIdx.x == 0) {
    const float tot = red[0] + red[1] + red[2] + red[3];
    num[b] = start_trans[tg] + end_trans[tg] + 1023.0f * trans[tg * NTAG + tg] + tot;
  }
}

// ---------------------------------------------------------------- final: sum_b (denom - num)
__global__ __launch_bounds__(128) void final_kernel(const float* __restrict__ denom,
                                                    const float* __restrict__ num,
                                                    float* __restrict__ out) {
  const int tid = threadIdx.x;
  float v = denom[tid] - num[tid];
#pragma unroll
  for (int off = 32; off > 0; off >>= 1) v += __shfl_xor(v, off, 64);
  __shared__ float red[2];
  if ((tid & 63) == 0) red[tid >> 6] = v;
  __syncthreads();
  if (tid == 0) out[0] = red[0] + red[1];
}

extern "C" void kernel_launch(void* const* d_in, const int* in_sizes, int n_in,
                              void* d_out, int out_size, void* d_ws, size_t ws_size,
                              hipStream_t stream) {
  const int* kmers = (const int*)d_in[0];
  const int* tags = (const int*)d_in[1];
  const float* emb = (const float*)d_in[2];
  const float* w_ih_f = (const float*)d_in[3];
  const float* w_hh_f = (const float*)d_in[4];
  const float* b_ih_f = (const float*)d_in[5];
  const float* b_hh_f = (const float*)d_in[6];
  const float* w_ih_b = (const float*)d_in[7];
  const float* w_hh_b = (const float*)d_in[8];
  const float* b_ih_b = (const float*)d_in[9];
  const float* b_hh_b = (const float*)d_in[10];
  const float* w_proj = (const float*)d_in[11];
  const float* b_proj = (const float*)d_in[12];
  const float* start_trans = (const float*)d_in[13];
  const float* end_trans = (const float*)d_in[14];
  const float* trans = (const float*)d_in[15];

  // Runtime segment-count selection: need = 100,663,296 + 268,435,456/nseg + 197,632.
  int nseg;
  if (ws_size >= 235078656ull) nseg = 2;
  else if (ws_size >= 167969792ull) nseg = 4;
  else if (ws_size >= 134415360ull) nseg = 8;
  else nseg = 16;  // 117,638,144 B
  const int Tseg = TT / nseg;
  const size_t xg_bytes = 268435456ull / (size_t)nseg;

  char* ws = (char*)d_ws;
  half4_t* x = (half4_t*)ws;                       // [0, 33.5M) f16; em aliases after xg done
  _Float16* h_cat = (_Float16*)(ws + 33554432);    // [33.5M, 100.7M)
  _Float16* xgbuf = (_Float16*)(ws + 100663296);   // [100.7M, +xg_bytes)
  _Float16* h_state = (_Float16*)(ws + 100663296 + xg_bytes);  // 65,536 B
  float* c_state = (float*)(ws + 100663296 + xg_bytes + 65536);  // 131,072 B
  float* denom = (float*)(ws + 100663296 + xg_bytes + 196608);   // 512 B
  float* num = denom + 128;
  float* em = (float*)ws;
  float* out = (float*)d_out;

  // zero h_state + c_state (196,608 B = 12,288 float4)
  hipLaunchKernelGGL(init_kernel, dim3(48), dim3(256), 0, stream, (float4_t*)h_state);
  hipLaunchKernelGGL(embed_kernel, dim3(16384), dim3(256), 0, stream, kmers, emb, x);
  for (int s = 0; s < nseg; ++s) {
    hipLaunchKernelGGL(xg_kernel, dim3(Tseg), dim3(1024), 0, stream, (const _Float16*)x,
                       w_ih_f, b_ih_f, b_hh_f, w_ih_b, b_ih_b, b_hh_b, xgbuf, s, Tseg);
    hipLaunchKernelGGL(lstm_kernel, dim3(16), dim3(512), 0, stream, (const _Float16*)xgbuf,
                       w_hh_f, w_hh_b, h_cat, h_state, c_state, s, Tseg);
  }
  hipLaunchKernelGGL(emis_kernel, dim3(2048), dim3(256), 0, stream, h_cat, w_proj, b_proj, em);
  hipLaunchKernelGGL(crf_kernel, dim3(32), dim3(64), 0, stream, em, trans, start_trans,
                     end_trans, denom);
  hipLaunchKernelGGL(numer_kernel, dim3(128), dim3(256), 0, stream, em, tags, trans, start_trans,
                     end_trans, num);
  hipLaunchKernelGGL(final_kernel, dim3(1), dim3(128), 0, stream, denom, num, out);
}

// Round 4
// 1703.612 us; speedup vs baseline: 1.0792x; 1.0792x over previous
//
#include <hip/hip_runtime.h>
#include <hip/hip_bf16.h>

typedef _Float16 half8_t __attribute__((ext_vector_type(8)));
typedef _Float16 half4_t __attribute__((ext_vector_type(4)));
typedef float float4_t __attribute__((ext_vector_type(4)));

#define TT 1024
#define BB 128
#define EE 128
#define HH 128
#define NTAG 64
#define ASTR 144  // LDS row stride (f16): 288 B/row, 16B-aligned fragments

__device__ __forceinline__ float fast_sigmoid(float x) {
  return __builtin_amdgcn_rcpf(1.0f + __builtin_amdgcn_exp2f(-1.44269504088896f * x));
}
__device__ __forceinline__ float fast_tanh(float x) {
  return 1.0f - 2.0f * __builtin_amdgcn_rcpf(1.0f + __builtin_amdgcn_exp2f(2.88539008177793f * x));
}
__device__ __forceinline__ float fast_exp(float x) {
  return __builtin_amdgcn_exp2f(x * 1.44269504088896f);
}
// LDS-only barrier: does NOT drain vmcnt -> global loads/stores stay in flight
// (__syncthreads emits s_waitcnt vmcnt(0) lgkmcnt(0) before s_barrier).
__device__ __forceinline__ void lds_barrier() {
  asm volatile("s_waitcnt lgkmcnt(0)\n\ts_barrier" ::: "memory");
}
// Single-wave LDS write->read fence (no cross-wave sync needed).
__device__ __forceinline__ void lds_fence() {
  asm volatile("s_waitcnt lgkmcnt(0)" ::: "memory");
}

// ---------------------------------------------------------------- init: zero LSTM state (196,608 B)
__global__ __launch_bounds__(256) void init_kernel(float4_t* __restrict__ p) {
  p[blockIdx.x * 256 + threadIdx.x] = (float4_t){0.f, 0.f, 0.f, 0.f};
}

// ---------------------------------------------------------------- embed: x[t,b,:] = f16(emb[kmers[t,b]])
__global__ __launch_bounds__(256) void embed_kernel(const int* __restrict__ kmers,
                                                    const float* __restrict__ emb,
                                                    half4_t* __restrict__ x) {
  const int g = blockIdx.x * 256 + threadIdx.x;  // T*B*32 threads
  const int row = g >> 5, seg = g & 31;
  const int km = kmers[row];
  const float4_t v = ((const float4_t*)(emb + (size_t)km * EE))[seg];
  half4_t o;
  o[0] = (_Float16)v[0]; o[1] = (_Float16)v[1];
  o[2] = (_Float16)v[2]; o[3] = (_Float16)v[3];
  x[(size_t)row * 32 + seg] = o;
}

// ---------------------------------------------------------------- xg segment: gates for Tseg steps, one dir per block
__global__ __launch_bounds__(1024, 1) void xg_kernel(
    const _Float16* __restrict__ x,
    const float* __restrict__ w_ih_f, const float* __restrict__ b_ih_f, const float* __restrict__ b_hh_f,
    const float* __restrict__ w_ih_b, const float* __restrict__ b_ih_b, const float* __restrict__ b_hh_b,
    _Float16* __restrict__ xgbuf, int s, int Tseg) {
  __shared__ _Float16 As[2][16 * ASTR];
  const int tid = threadIdx.x;
  const int wave = tid >> 6, lane = tid & 63;
  const int n16 = lane & 15, quad = lane >> 4;
  const int nblk = Tseg >> 1;
  const int dir = (blockIdx.x >= nblk) ? 1 : 0;
  const int bb = dir ? (blockIdx.x - nblk) : blockIdx.x;

  const float* wih = dir ? w_ih_b : w_ih_f;
  const float* bih = dir ? b_ih_b : b_ih_f;
  const float* bhh = dir ? b_hh_b : b_hh_f;

  half8_t bf[2][4];  // [j][kf]
  float bias[2];
  int gj[2], wj[2];
#pragma unroll
  for (int j = 0; j < 2; ++j) {
    const int nf = wave * 2 + j;  // 0..31 n-tiles (4 gates x 8 hu-tiles)
    gj[j] = nf >> 3; wj[j] = nf & 7;
    const int row = gj[j] * HH + wj[j] * 16 + n16;
    bias[j] = bih[row] + bhh[row];
#pragma unroll
    for (int kf = 0; kf < 4; ++kf) {
      const float* src = wih + row * EE + kf * 32 + quad * 8;
#pragma unroll
      for (int i = 0; i < 8; ++i) bf[j][kf][i] = (_Float16)src[i];
    }
  }
  const int sr = tid >> 4, scb = tid & 15;
#define MTG(mi) (((dir) ? (TT - 1 - s * Tseg - (2 * bb + ((mi) >> 3))) : (s * Tseg + (2 * bb + ((mi) >> 3)))) * 8 + ((mi) & 7))
  if (tid < 256)
    *(half8_t*)(&As[0][sr * ASTR + scb * 8]) =
        *(const half8_t*)(x + ((size_t)MTG(0) * 16 + sr) * 128 + scb * 8);
  lds_barrier();
  for (int mi = 0; mi < 16; ++mi) {
    half8_t stg = {};
    if (tid < 256 && mi < 15)
      stg = *(const half8_t*)(x + ((size_t)MTG(mi + 1) * 16 + sr) * 128 + scb * 8);
    const _Float16* Ab = &As[mi & 1][0];
    half8_t af[4];
#pragma unroll
    for (int kf = 0; kf < 4; ++kf) af[kf] = *(const half8_t*)(Ab + n16 * ASTR + kf * 32 + quad * 8);
    float4_t acc[2];
#pragma unroll
    for (int j = 0; j < 2; ++j) acc[j] = (float4_t){bias[j], bias[j], bias[j], bias[j]};
#pragma unroll
    for (int kf = 0; kf < 4; ++kf)
#pragma unroll
      for (int j = 0; j < 2; ++j)
        acc[j] = __builtin_amdgcn_mfma_f32_16x16x32_f16(af[kf], bf[j][kf], acc[j], 0, 0, 0);
    const int mtl = (2 * bb + (mi >> 3)) * 8 + (mi & 7);
#pragma unroll
    for (int j = 0; j < 2; ++j) {
      half4_t o;
#pragma unroll
      for (int r = 0; r < 4; ++r) o[r] = (_Float16)acc[j][r];
      *(half4_t*)(xgbuf + (size_t)dir * Tseg * 65536 +
                  (((size_t)mtl * 8 + wj[j]) * 4 + gj[j]) * 256 + lane * 4) = o;
    }
    if (tid < 256 && mi < 15)
      *(half8_t*)(&As[(mi + 1) & 1][sr * ASTR + scb * 8]) = stg;
    lds_barrier();
  }
#undef MTG
}

// ---------------------------------------------------------------- bidirectional LSTM segment (recurrence only)
__global__ __launch_bounds__(512, 2) void lstm_kernel(
    const _Float16* __restrict__ xgbuf,
    const float* __restrict__ w_hh_f, const float* __restrict__ w_hh_b,
    _Float16* __restrict__ h_cat, _Float16* __restrict__ h_state, float* __restrict__ c_state,
    int s, int Tseg) {
  __shared__ _Float16 A[2][16 * ASTR];
  const int wg = blockIdx.x;
  const int dir = wg >> 3, chunk = wg & 7;
  const int b0 = chunk * 16;
  const float* w_hh = dir ? w_hh_b : w_hh_f;
  const int tid = threadIdx.x;
  const int wave = tid >> 6, lane = tid & 63;
  const int n16 = lane & 15, quad = lane >> 4;
  const int hu = wave * 16 + n16;

  half8_t bf[4][4];  // [gate][kf] of W_hh (K=128)
#pragma unroll
  for (int g = 0; g < 4; ++g) {
    const int ng = g * HH + hu;
#pragma unroll
    for (int kf = 0; kf < 4; ++kf) {
      const float* src = w_hh + ng * HH + kf * 32 + quad * 8;
#pragma unroll
      for (int i = 0; i < 8; ++i) bf[g][kf][i] = (_Float16)src[i];
    }
  }
  const int sidx = ((wg * 8 + wave) * 64 + lane) * 4;
  half4_t h4 = *(const half4_t*)(h_state + sidx);
  float4_t c4 = *(const float4_t*)(c_state + sidx);
  float c[4] = {c4[0], c4[1], c4[2], c4[3]};
#pragma unroll
  for (int r = 0; r < 4; ++r) A[0][(quad * 4 + r) * ASTR + hu] = h4[r];

  const _Float16* xgw = xgbuf + (size_t)dir * Tseg * 65536 + (chunk * 8 + wave) * 1024 + lane * 4;
  half4_t xv[4];
#pragma unroll
  for (int g = 0; g < 4; ++g) xv[g] = *(const half4_t*)(xgw + g * 256);
  half4_t hlast = h4;
  lds_barrier();

  for (int il = 0; il < Tseg; ++il) {
    half4_t xn[4] = {};
    if (il + 1 < Tseg) {
#pragma unroll
      for (int g = 0; g < 4; ++g)
        xn[g] = *(const half4_t*)(xgw + (size_t)(il + 1) * 65536 + g * 256);
    }
    lds_barrier();  // h_{i-1} in buf[il&1] ready (LDS-only wait: global ops stay in flight)
    const _Float16* Ab = &A[il & 1][0];
    _Float16* An = &A[(il + 1) & 1][0];
    half8_t af[4];
#pragma unroll
    for (int kf = 0; kf < 4; ++kf) af[kf] = *(const half8_t*)(Ab + n16 * ASTR + kf * 32 + quad * 8);
    float4_t acc[4];
#pragma unroll
    for (int g = 0; g < 4; ++g)
      acc[g] = (float4_t){(float)xv[g][0], (float)xv[g][1], (float)xv[g][2], (float)xv[g][3]};
#pragma unroll
    for (int kf = 0; kf < 4; ++kf)
#pragma unroll
      for (int g = 0; g < 4; ++g)
        acc[g] = __builtin_amdgcn_mfma_f32_16x16x32_f16(af[kf], bf[g][kf], acc[g], 0, 0, 0);
#pragma unroll
    for (int g = 0; g < 4; ++g) xv[g] = xn[g];
    const int i = s * Tseg + il;
    const int te = dir ? (TT - 1 - i) : i;
    _Float16* gptr = h_cat + ((size_t)te * BB + b0 + quad * 4) * 256 + dir * HH + hu;
    _Float16 hh4[4];
#pragma unroll
    for (int r = 0; r < 4; ++r) {
      const float gi = acc[0][r], gf = acc[1][r], gg = acc[2][r], go = acc[3][r];
      const float cr = fast_sigmoid(gf) * c[r] + fast_sigmoid(gi) * fast_tanh(gg);
      c[r] = cr;
      const float hv = fast_sigmoid(go) * fast_tanh(cr);
      const _Float16 hh = (_Float16)hv;
      An[(quad * 4 + r) * ASTR + hu] = hh;  // LDS first (on chain)
      hh4[r] = hh;
      hlast[r] = hh;
    }
#pragma unroll
    for (int r = 0; r < 4; ++r) gptr[r * 256] = hh4[r];  // global: fire-and-forget
  }
  *(half4_t*)(h_state + sidx) = hlast;
  c4[0] = c[0]; c4[1] = c[1]; c4[2] = c[2]; c4[3] = c[3];
  *(float4_t*)(c_state + sidx) = c4;
}

// ---------------------------------------------------------------- emissions: em = h_cat @ w_proj^T + b_proj
__global__ __launch_bounds__(256) void emis_kernel(const _Float16* __restrict__ h_cat,
                                                   const float* __restrict__ w_proj,
                                                   const float* __restrict__ b_proj,
                                                   float* __restrict__ em) {
  const int tid = threadIdx.x;
  const int wave = tid >> 6, lane = tid & 63;
  const int n16 = lane & 15, quad = lane >> 4;
  const size_t row0 = (size_t)blockIdx.x * 64 + wave * 16;

  half8_t bf[4][8];
#pragma unroll
  for (int nt = 0; nt < 4; ++nt) {
    const float* wp = w_proj + (nt * 16 + n16) * 256;
#pragma unroll
    for (int kf = 0; kf < 8; ++kf) {
      const int kb = kf * 32 + quad * 8;
#pragma unroll
      for (int i = 0; i < 8; ++i) bf[nt][kf][i] = (_Float16)wp[kb + i];
    }
  }
  float4_t acc[4];
#pragma unroll
  for (int nt = 0; nt < 4; ++nt) {
    const float bv = b_proj[nt * 16 + n16];
    acc[nt] = (float4_t){bv, bv, bv, bv};
  }
#pragma unroll
  for (int kf = 0; kf < 8; ++kf) {
    half8_t af = *(const half8_t*)(h_cat + (row0 + n16) * 256 + kf * 32 + quad * 8);
#pragma unroll
    for (int nt = 0; nt < 4; ++nt)
      acc[nt] = __builtin_amdgcn_mfma_f32_16x16x32_f16(af, bf[nt][kf], acc[nt], 0, 0, 0);
  }
#pragma unroll
  for (int nt = 0; nt < 4; ++nt)
#pragma unroll
    for (int r = 0; r < 4; ++r)
      em[(row0 + quad * 4 + r) * NTAG + nt * 16 + n16] = acc[nt][r];
}

// ---------------------------------------------------------------- CRF forward, scaled LINEAR space
// alpha_{t+1} = (alpha_t @ E) * exp(em_t), rescaled by max; logZ accumulates log(scale).
// 1 wave per wg, 4 batches (b = n16&3, duplicated over n16 groups). No s_barrier (single wave).
__global__ __launch_bounds__(64) void crf_kernel(const float* __restrict__ em,
                                                 const float* __restrict__ trans,
                                                 const float* __restrict__ start_trans,
                                                 const float* __restrict__ end_trans,
                                                 float* __restrict__ denom) {
  __shared__ float tmp[2][16 * 68];  // double-buffered C->A relayout scratch
  const int lane = threadIdx.x;
  const int n16 = lane & 15, quad = lane >> 4;
  const int b = n16 & 3;
  const int gb = blockIdx.x * 4 + b;

  half8_t ef[4][2];  // E = exp(trans) in B-frag layout [nt][kf]
#pragma unroll
  for (int nt = 0; nt < 4; ++nt)
#pragma unroll
    for (int kf = 0; kf < 2; ++kf)
#pragma unroll
      for (int i = 0; i < 8; ++i)
        ef[nt][kf][i] = (_Float16)fast_exp(trans[(kf * 32 + quad * 8 + i) * NTAG + nt * 16 + n16]);

  float sv[16], et[16];
#pragma unroll
  for (int kf = 0; kf < 2; ++kf) {
    const int j0 = kf * 32 + quad * 8;
    float4_t s0 = *(const float4_t*)(start_trans + j0);
    float4_t s1 = *(const float4_t*)(start_trans + j0 + 4);
    float4_t e0 = *(const float4_t*)(end_trans + j0);
    float4_t e1 = *(const float4_t*)(end_trans + j0 + 4);
    float4_t m0v = *(const float4_t*)(em + (size_t)gb * NTAG + j0);
    float4_t m1v = *(const float4_t*)(em + (size_t)gb * NTAG + j0 + 4);
#pragma unroll
    for (int i = 0; i < 4; ++i) {
      sv[kf * 8 + i] = s0[i] + m0v[i];
      sv[kf * 8 + 4 + i] = s1[i] + m1v[i];
      et[kf * 8 + i] = e0[i];
      et[kf * 8 + 4 + i] = e1[i];
    }
  }
  // initial max + normalize: alpha_1 = exp(s_1 - m0)
  float m0;
  {
    float mx[8];
#pragma unroll
    for (int i = 0; i < 8; ++i) mx[i] = fmaxf(sv[i], sv[8 + i]);
#pragma unroll
    for (int i = 0; i < 4; ++i) mx[i] = fmaxf(mx[i], mx[4 + i]);
    m0 = fmaxf(fmaxf(mx[0], mx[1]), fmaxf(mx[2], mx[3]));
    m0 = fmaxf(m0, __shfl_xor(m0, 16, 64));
    m0 = fmaxf(m0, __shfl_xor(m0, 32, 64));
  }
  half8_t pa[2];  // alpha in A-frag layout (f16)
  float av[16];   // alpha (f32 copy, for final sum)
#pragma unroll
  for (int kf = 0; kf < 2; ++kf)
#pragma unroll
    for (int i = 0; i < 8; ++i) {
      av[kf * 8 + i] = fast_exp(sv[kf * 8 + i] - m0);
      pa[kf][i] = (_Float16)av[kf * 8 + i];
    }
  float lz2 = 0.f;  // accumulated log2(scale)

  float4_t emn[4];  // prefetched em for next t
#pragma unroll
  for (int kf = 0; kf < 2; ++kf) {
    const size_t base = ((size_t)1 * BB + gb) * NTAG + kf * 32 + quad * 8;
    emn[kf * 2] = *(const float4_t*)(em + base);
    emn[kf * 2 + 1] = *(const float4_t*)(em + base + 4);
  }

  for (int t = 1; t < TT; ++t) {
    float4_t emc[4];
#pragma unroll
    for (int q = 0; q < 4; ++q) emc[q] = emn[q];
    if (t + 1 < TT) {
#pragma unroll
      for (int kf = 0; kf < 2; ++kf) {
        const size_t base = ((size_t)(t + 1) * BB + gb) * NTAG + kf * 32 + quad * 8;
        emn[kf * 2] = *(const float4_t*)(em + base);
        emn[kf * 2 + 1] = *(const float4_t*)(em + base + 4);
      }
    }
    float g[16];  // exp(em_t) — independent of recurrence, schedules off-chain
#pragma unroll
    for (int q = 0; q < 4; ++q)
#pragma unroll
      for (int i = 0; i < 4; ++i) g[q * 4 + i] = fast_exp(emc[q][i]);

    float4_t acc[4];
#pragma unroll
    for (int nt = 0; nt < 4; ++nt) acc[nt] = (float4_t){0.f, 0.f, 0.f, 0.f};
#pragma unroll
    for (int kf = 0; kf < 2; ++kf)
#pragma unroll
      for (int nt = 0; nt < 4; ++nt)
        acc[nt] = __builtin_amdgcn_mfma_f32_16x16x32_f16(pa[kf], ef[nt][kf], acc[nt], 0, 0, 0);
    // C->A relayout: all lanes write their D rows (rows 4..15 are duplicates, unread)
    float* tb = tmp[t & 1];
#pragma unroll
    for (int nt = 0; nt < 4; ++nt)
#pragma unroll
      for (int r = 0; r < 4; ++r) tb[(quad * 4 + r) * 68 + nt * 16 + n16] = acc[nt][r];
    lds_fence();
    // read q[b][j] at this lane's A-frag positions, fold in exp(em), rescale
#pragma unroll
    for (int kf = 0; kf < 2; ++kf) {
      float4_t v0 = *(const float4_t*)(&tb[b * 68 + kf * 32 + quad * 8]);
      float4_t v1 = *(const float4_t*)(&tb[b * 68 + kf * 32 + quad * 8 + 4]);
#pragma unroll
      for (int i = 0; i < 4; ++i) {
        av[kf * 8 + i] = v0[i] * g[kf * 8 + i];
        av[kf * 8 + 4 + i] = v1[i] * g[kf * 8 + 4 + i];
      }
    }
    float mx[8];
#pragma unroll
    for (int i = 0; i < 8; ++i) mx[i] = fmaxf(av[i], av[8 + i]);
#pragma unroll
    for (int i = 0; i < 4; ++i) mx[i] = fmaxf(mx[i], mx[4 + i]);
    float c = fmaxf(fmaxf(mx[0], mx[1]), fmaxf(mx[2], mx[3]));
    c = fmaxf(c, __shfl_xor(c, 16, 64));
    c = fmaxf(c, __shfl_xor(c, 32, 64));
    lz2 += __builtin_amdgcn_logf(c);  // log2; off critical path
    const float rc = __builtin_amdgcn_rcpf(c);
#pragma unroll
    for (int kf = 0; kf < 2; ++kf)
#pragma unroll
      for (int i = 0; i < 8; ++i) {
        av[kf * 8 + i] *= rc;
        pa[kf][i] = (_Float16)av[kf * 8 + i];
      }
  }

  // denom = m0 + ln2*lz2 + ln( sum_j alpha[j]*exp(end[j]) )
  float w = 0.f;
#pragma unroll
  for (int i = 0; i < 16; ++i) w += av[i] * fast_exp(et[i]);
  w += __shfl_xor(w, 16, 64);
  w += __shfl_xor(w, 32, 64);
  if (lane < 4)
    denom[blockIdx.x * 4 + lane] = m0 + 0.693147180559945f * (lz2 + __builtin_amdgcn_logf(w));
}

// ---------------------------------------------------------------- numerator (tags constant over time)
__global__ __launch_bounds__(256) void numer_kernel(const float* __restrict__ em,
                                                    const int* __restrict__ tags,
                                                    const float* __restrict__ trans,
                                                    const float* __restrict__ start_trans,
                                                    const float* __restrict__ end_trans,
                                                    float* __restrict__ num) {
  const int b = blockIdx.x;
  const int tg = tags[b];
  float acc = 0.f;
  for (int t = threadIdx.x; t < TT; t += 256)
    acc += em[((size_t)t * BB + b) * NTAG + tg];
#pragma unroll
  for (int off = 32; off > 0; off >>= 1) acc += __shfl_xor(acc, off, 64);
  __shared__ float red[4];
  if ((threadIdx.x & 63) == 0) red[threadIdx.x >> 6] = acc;
  __syncthreads();
  if (threadIdx.x == 0) {
    const float tot = red[0] + red[1] + red[2] + red[3];
    num[b] = start_trans[tg] + end_trans[tg] + 1023.0f * trans[tg * NTAG + tg] + tot;
  }
}

// ---------------------------------------------------------------- final: sum_b (denom - num)
__global__ __launch_bounds__(128) void final_kernel(const float* __restrict__ denom,
                                                    const float* __restrict__ num,
                                                    float* __restrict__ out) {
  const int tid = threadIdx.x;
  float v = denom[tid] - num[tid];
#pragma unroll
  for (int off = 32; off > 0; off >>= 1) v += __shfl_xor(v, off, 64);
  __shared__ float red[2];
  if ((tid & 63) == 0) red[tid >> 6] = v;
  __syncthreads();
  if (tid == 0) out[0] = red[0] + red[1];
}

extern "C" void kernel_launch(void* const* d_in, const int* in_sizes, int n_in,
                              void* d_out, int out_size, void* d_ws, size_t ws_size,
                              hipStream_t stream) {
  const int* kmers = (const int*)d_in[0];
  const int* tags = (const int*)d_in[1];
  const float* emb = (const float*)d_in[2];
  const float* w_ih_f = (const float*)d_in[3];
  const float* w_hh_f = (const float*)d_in[4];
  const float* b_ih_f = (const float*)d_in[5];
  const float* b_hh_f = (const float*)d_in[6];
  const float* w_ih_b = (const float*)d_in[7];
  const float* w_hh_b = (const float*)d_in[8];
  const float* b_ih_b = (const float*)d_in[9];
  const float* b_hh_b = (const float*)d_in[10];
  const float* w_proj = (const float*)d_in[11];
  const float* b_proj = (const float*)d_in[12];
  const float* start_trans = (const float*)d_in[13];
  const float* end_trans = (const float*)d_in[14];
  const float* trans = (const float*)d_in[15];

  // Runtime segment-count selection: need = 100,663,296 + 268,435,456/nseg + 197,632.
  int nseg;
  if (ws_size >= 235078656ull) nseg = 2;
  else if (ws_size >= 167969792ull) nseg = 4;
  else if (ws_size >= 134415360ull) nseg = 8;
  else nseg = 16;  // 117,638,144 B
  const int Tseg = TT / nseg;
  const size_t xg_bytes = 268435456ull / (size_t)nseg;

  char* ws = (char*)d_ws;
  half4_t* x = (half4_t*)ws;                       // [0, 33.5M) f16; em aliases after xg done
  _Float16* h_cat = (_Float16*)(ws + 33554432);    // [33.5M, 100.7M)
  _Float16* xgbuf = (_Float16*)(ws + 100663296);   // [100.7M, +xg_bytes)
  _Float16* h_state = (_Float16*)(ws + 100663296 + xg_bytes);   // 65,536 B
  float* c_state = (float*)(ws + 100663296 + xg_bytes + 65536); // 131,072 B
  float* denom = (float*)(ws + 100663296 + xg_bytes + 196608);  // 512 B
  float* num = denom + 128;
  float* em = (float*)ws;
  float* out = (float*)d_out;

  hipLaunchKernelGGL(init_kernel, dim3(48), dim3(256), 0, stream, (float4_t*)h_state);
  hipLaunchKernelGGL(embed_kernel, dim3(16384), dim3(256), 0, stream, kmers, emb, x);
  for (int s = 0; s < nseg; ++s) {
    hipLaunchKernelGGL(xg_kernel, dim3(Tseg), dim3(1024), 0, stream, (const _Float16*)x,
                       w_ih_f, b_ih_f, b_hh_f, w_ih_b, b_ih_b, b_hh_b, xgbuf, s, Tseg);
    hipLaunchKernelGGL(lstm_kernel, dim3(16), dim3(512), 0, stream, (const _Float16*)xgbuf,
                       w_hh_f, w_hh_b, h_cat, h_state, c_state, s, Tseg);
  }
  hipLaunchKernelGGL(emis_kernel, dim3(2048), dim3(256), 0, stream, h_cat, w_proj, b_proj, em);
  hipLaunchKernelGGL(crf_kernel, dim3(32), dim3(64), 0, stream, em, trans, start_trans,
                     end_trans, denom);
  hipLaunchKernelGGL(numer_kernel, dim3(128), dim3(256), 0, stream, em, tags, trans, start_trans,
                     end_trans, num);
  hipLaunchKernelGGL(final_kernel, dim3(1), dim3(128), 0, stream, denom, num, out);
}

// Round 6
// 1417.097 us; speedup vs baseline: 1.2974x; 1.2022x over previous
//
#include <hip/hip_runtime.h>
#include <hip/hip_bf16.h>

typedef _Float16 half8_t __attribute__((ext_vector_type(8)));
typedef _Float16 half4_t __attribute__((ext_vector_type(4)));
typedef _Float16 half2_t __attribute__((ext_vector_type(2)));
typedef float float4_t __attribute__((ext_vector_type(4)));

#define TT 1024
#define BB 128
#define EE 128
#define HH 128
#define NTAG 64
#define ASTR 144  // LDS row stride (f16): 288 B/row, 16B-aligned fragments

__device__ __forceinline__ float fast_exp(float x) {
  return __builtin_amdgcn_exp2f(x * 1.44269504088896f);
}
// LDS-only barrier: does NOT drain vmcnt -> global loads/stores stay in flight.
__device__ __forceinline__ void lds_barrier() {
  asm volatile("s_waitcnt lgkmcnt(0)\n\ts_barrier" ::: "memory");
}
// Single-wave LDS write->read fence.
__device__ __forceinline__ void lds_fence() {
  asm volatile("s_waitcnt lgkmcnt(0)" ::: "memory");
}
// cvt_pkrtz returns __fp16x2; bit-cast to our _Float16x2.
__device__ __forceinline__ half2_t cvt_pk(float a, float b) {
  return __builtin_bit_cast(half2_t, __builtin_amdgcn_cvt_pkrtz(a, b));
}

__device__ __forceinline__ half2_t h2bc(float v) {
  _Float16 h = (_Float16)v;
  half2_t r; r[0] = h; r[1] = h;
  return r;
}
// tanh poly: odd deg-7, exact at x={1,1.5,2}, clamp +-2 (worst err ~2e-3 in-range)
__device__ __forceinline__ half2_t tanh_p(half2_t x) {
  half2_t y = __builtin_elementwise_min(__builtin_elementwise_max(x, h2bc(-2.f)), h2bc(2.f));
  half2_t u = y * y;
  half2_t p = u * h2bc(-0.0076687f) + h2bc(0.0746465f);
  p = u * p + h2bc(-0.3053838f);
  p = u * p + h2bc(1.0f);
  return y * p;
}
__device__ __forceinline__ half2_t sig_p(half2_t x) {
  half2_t y = __builtin_elementwise_min(
      __builtin_elementwise_max(x * h2bc(0.5f), h2bc(-2.f)), h2bc(2.f));
  half2_t u = y * y;
  half2_t p = u * h2bc(-0.0076687f) + h2bc(0.0746465f);
  p = u * p + h2bc(-0.3053838f);
  p = u * p + h2bc(1.0f);
  return (y * h2bc(0.5f)) * p + h2bc(0.5f);
}

// ---------------------------------------------------------------- init: zero LSTM state
__global__ __launch_bounds__(256) void init_kernel(float4_t* __restrict__ p) {
  p[blockIdx.x * 256 + threadIdx.x] = (float4_t){0.f, 0.f, 0.f, 0.f};
}

// ---------------------------------------------------------------- embed
__global__ __launch_bounds__(256) void embed_kernel(const int* __restrict__ kmers,
                                                    const float* __restrict__ emb,
                                                    half4_t* __restrict__ x) {
  const int g = blockIdx.x * 256 + threadIdx.x;
  const int row = g >> 5, seg = g & 31;
  const int km = kmers[row];
  const float4_t v = ((const float4_t*)(emb + (size_t)km * EE))[seg];
  half4_t o;
  o[0] = (_Float16)v[0]; o[1] = (_Float16)v[1];
  o[2] = (_Float16)v[2]; o[3] = (_Float16)v[3];
  x[(size_t)row * 32 + seg] = o;
}

// ---------------------------------------------------------------- xg segment
__global__ __launch_bounds__(1024, 1) void xg_kernel(
    const _Float16* __restrict__ x,
    const float* __restrict__ w_ih_f, const float* __restrict__ b_ih_f, const float* __restrict__ b_hh_f,
    const float* __restrict__ w_ih_b, const float* __restrict__ b_ih_b, const float* __restrict__ b_hh_b,
    _Float16* __restrict__ xgbuf, int s, int Tseg) {
  __shared__ _Float16 As[2][16 * ASTR];
  const int tid = threadIdx.x;
  const int wave = tid >> 6, lane = tid & 63;
  const int n16 = lane & 15, quad = lane >> 4;
  const int nblk = Tseg >> 1;
  const int dir = (blockIdx.x >= nblk) ? 1 : 0;
  const int bb = dir ? (blockIdx.x - nblk) : blockIdx.x;

  const float* wih = dir ? w_ih_b : w_ih_f;
  const float* bih = dir ? b_ih_b : b_ih_f;
  const float* bhh = dir ? b_hh_b : b_hh_f;

  half8_t bf[2][4];
  float bias[2];
  int gj[2], wj[2];
#pragma unroll
  for (int j = 0; j < 2; ++j) {
    const int nf = wave * 2 + j;
    gj[j] = nf >> 3; wj[j] = nf & 7;
    const int row = gj[j] * HH + wj[j] * 16 + n16;
    bias[j] = bih[row] + bhh[row];
#pragma unroll
    for (int kf = 0; kf < 4; ++kf) {
      const float* src = wih + row * EE + kf * 32 + quad * 8;
#pragma unroll
      for (int i = 0; i < 8; ++i) bf[j][kf][i] = (_Float16)src[i];
    }
  }
  const int sr = tid >> 4, scb = tid & 15;
#define MTG(mi) (((dir) ? (TT - 1 - s * Tseg - (2 * bb + ((mi) >> 3))) : (s * Tseg + (2 * bb + ((mi) >> 3)))) * 8 + ((mi) & 7))
  if (tid < 256)
    *(half8_t*)(&As[0][sr * ASTR + scb * 8]) =
        *(const half8_t*)(x + ((size_t)MTG(0) * 16 + sr) * 128 + scb * 8);
  lds_barrier();
  for (int mi = 0; mi < 16; ++mi) {
    half8_t stg = {};
    if (tid < 256 && mi < 15)
      stg = *(const half8_t*)(x + ((size_t)MTG(mi + 1) * 16 + sr) * 128 + scb * 8);
    const _Float16* Ab = &As[mi & 1][0];
    half8_t af[4];
#pragma unroll
    for (int kf = 0; kf < 4; ++kf) af[kf] = *(const half8_t*)(Ab + n16 * ASTR + kf * 32 + quad * 8);
    float4_t acc[2];
#pragma unroll
    for (int j = 0; j < 2; ++j) acc[j] = (float4_t){bias[j], bias[j], bias[j], bias[j]};
#pragma unroll
    for (int kf = 0; kf < 4; ++kf)
#pragma unroll
      for (int j = 0; j < 2; ++j)
        acc[j] = __builtin_amdgcn_mfma_f32_16x16x32_f16(af[kf], bf[j][kf], acc[j], 0, 0, 0);
    const int mtl = (2 * bb + (mi >> 3)) * 8 + (mi & 7);
#pragma unroll
    for (int j = 0; j < 2; ++j) {
      half4_t o;
#pragma unroll
      for (int r = 0; r < 4; ++r) o[r] = (_Float16)acc[j][r];
      *(half4_t*)(xgbuf + (size_t)dir * Tseg * 65536 +
                  (((size_t)mtl * 8 + wj[j]) * 4 + gj[j]) * 256 + lane * 4) = o;
    }
    if (tid < 256 && mi < 15)
      *(half8_t*)(&As[(mi + 1) & 1][sr * ASTR + scb * 8]) = stg;
    lds_barrier();
  }
#undef MTG
}

// ---------------------------------------------------------------- bidirectional LSTM segment
// Epilogue fully in packed f16 (poly activations) — no transcendentals.
__global__ __launch_bounds__(512, 2) void lstm_kernel(
    const _Float16* __restrict__ xgbuf,
    const float* __restrict__ w_hh_f, const float* __restrict__ w_hh_b,
    _Float16* __restrict__ h_cat, _Float16* __restrict__ h_state, float* __restrict__ c_state,
    int s, int Tseg) {
  __shared__ _Float16 A[2][16 * ASTR];
  const int wg = blockIdx.x;
  const int dir = wg >> 3, chunk = wg & 7;
  const int b0 = chunk * 16;
  const float* w_hh = dir ? w_hh_b : w_hh_f;
  const int tid = threadIdx.x;
  const int wave = tid >> 6, lane = tid & 63;
  const int n16 = lane & 15, quad = lane >> 4;
  const int hu = wave * 16 + n16;

  half8_t bf[4][4];
#pragma unroll
  for (int g = 0; g < 4; ++g) {
    const int ng = g * HH + hu;
#pragma unroll
    for (int kf = 0; kf < 4; ++kf) {
      const float* src = w_hh + ng * HH + kf * 32 + quad * 8;
#pragma unroll
      for (int i = 0; i < 8; ++i) bf[g][kf][i] = (_Float16)src[i];
    }
  }
  const int sidx = ((wg * 8 + wave) * 64 + lane) * 4;
  half4_t h4 = *(const half4_t*)(h_state + sidx);
  float4_t c4 = *(const float4_t*)(c_state + sidx);
  half2_t c2[2];
  c2[0] = cvt_pk(c4[0], c4[1]);
  c2[1] = cvt_pk(c4[2], c4[3]);
#pragma unroll
  for (int r = 0; r < 4; ++r) A[0][(quad * 4 + r) * ASTR + hu] = h4[r];

  const _Float16* xgw = xgbuf + (size_t)dir * Tseg * 65536 + (chunk * 8 + wave) * 1024 + lane * 4;
  half4_t xv[4];
#pragma unroll
  for (int g = 0; g < 4; ++g) xv[g] = *(const half4_t*)(xgw + g * 256);
  half4_t hlast = h4;
  lds_barrier();

  for (int il = 0; il < Tseg; ++il) {
    half4_t xn[4] = {};
    if (il + 1 < Tseg) {
#pragma unroll
      for (int g = 0; g < 4; ++g)
        xn[g] = *(const half4_t*)(xgw + (size_t)(il + 1) * 65536 + g * 256);
    }
    lds_barrier();  // h_{i-1} ready in buf[il&1]; global ops stay in flight
    const _Float16* Ab = &A[il & 1][0];
    _Float16* An = &A[(il + 1) & 1][0];
    half8_t af[4];
#pragma unroll
    for (int kf = 0; kf < 4; ++kf) af[kf] = *(const half8_t*)(Ab + n16 * ASTR + kf * 32 + quad * 8);
    float4_t acc[4] = {{0.f, 0.f, 0.f, 0.f}, {0.f, 0.f, 0.f, 0.f},
                       {0.f, 0.f, 0.f, 0.f}, {0.f, 0.f, 0.f, 0.f}};
#pragma unroll
    for (int kf = 0; kf < 4; ++kf)
#pragma unroll
      for (int g = 0; g < 4; ++g)
        acc[g] = __builtin_amdgcn_mfma_f32_16x16x32_f16(af[kf], bf[g][kf], acc[g], 0, 0, 0);
    // gates = MFMA + xg, packed f16 pairs (pair p covers rows 2p,2p+1)
    half2_t gp[2][4];
#pragma unroll
    for (int g = 0; g < 4; ++g) {
      const half2_t* xp = (const half2_t*)&xv[g];
      gp[0][g] = cvt_pk(acc[g][0], acc[g][1]) + xp[0];
      gp[1][g] = cvt_pk(acc[g][2], acc[g][3]) + xp[1];
    }
#pragma unroll
    for (int g = 0; g < 4; ++g) xv[g] = xn[g];
    const int i = s * Tseg + il;
    const int te = dir ? (TT - 1 - i) : i;
    _Float16* gptr = h_cat + ((size_t)te * BB + b0 + quad * 4) * 256 + dir * HH + hu;
#pragma unroll
    for (int p = 0; p < 2; ++p) {
      const half2_t i_ = sig_p(gp[p][0]);
      const half2_t f_ = sig_p(gp[p][1]);
      const half2_t g_ = tanh_p(gp[p][2]);
      const half2_t o_ = sig_p(gp[p][3]);
      c2[p] = f_ * c2[p] + i_ * g_;
      const half2_t hh = o_ * tanh_p(c2[p]);
      An[(quad * 4 + 2 * p) * ASTR + hu] = hh[0];
      An[(quad * 4 + 2 * p + 1) * ASTR + hu] = hh[1];
      gptr[(2 * p) * 256] = hh[0];
      gptr[(2 * p + 1) * 256] = hh[1];
      hlast[2 * p] = hh[0];
      hlast[2 * p + 1] = hh[1];
    }
  }
  *(half4_t*)(h_state + sidx) = hlast;
  c4[0] = (float)c2[0][0]; c4[1] = (float)c2[0][1];
  c4[2] = (float)c2[1][0]; c4[3] = (float)c2[1][1];
  *(float4_t*)(c_state + sidx) = c4;
}

// ---------------------------------------------------------------- emissions: em f32 + expem f16
__global__ __launch_bounds__(256) void emis_kernel(const _Float16* __restrict__ h_cat,
                                                   const float* __restrict__ w_proj,
                                                   const float* __restrict__ b_proj,
                                                   float* __restrict__ em,
                                                   _Float16* __restrict__ expem) {
  const int tid = threadIdx.x;
  const int wave = tid >> 6, lane = tid & 63;
  const int n16 = lane & 15, quad = lane >> 4;
  const size_t row0 = (size_t)blockIdx.x * 64 + wave * 16;

  half8_t bf[4][8];
#pragma unroll
  for (int nt = 0; nt < 4; ++nt) {
    const float* wp = w_proj + (nt * 16 + n16) * 256;
#pragma unroll
    for (int kf = 0; kf < 8; ++kf) {
      const int kb = kf * 32 + quad * 8;
#pragma unroll
      for (int i = 0; i < 8; ++i) bf[nt][kf][i] = (_Float16)wp[kb + i];
    }
  }
  float4_t acc[4];
#pragma unroll
  for (int nt = 0; nt < 4; ++nt) {
    const float bv = b_proj[nt * 16 + n16];
    acc[nt] = (float4_t){bv, bv, bv, bv};
  }
#pragma unroll
  for (int kf = 0; kf < 8; ++kf) {
    half8_t af = *(const half8_t*)(h_cat + (row0 + n16) * 256 + kf * 32 + quad * 8);
#pragma unroll
    for (int nt = 0; nt < 4; ++nt)
      acc[nt] = __builtin_amdgcn_mfma_f32_16x16x32_f16(af, bf[nt][kf], acc[nt], 0, 0, 0);
  }
#pragma unroll
  for (int nt = 0; nt < 4; ++nt)
#pragma unroll
    for (int r = 0; r < 4; ++r) {
      const size_t idx = (row0 + quad * 4 + r) * NTAG + nt * 16 + n16;
      em[idx] = acc[nt][r];
      expem[idx] = (_Float16)fast_exp(acc[nt][r]);
    }
}

// ---------------------------------------------------------------- CRF forward, scaled linear space
// alpha' = (alpha @ (exp(trans)/64)) * expem; renorm every 16 steps; logZ bookkeeping at end.
__global__ __launch_bounds__(64) void crf_kernel(const float* __restrict__ em,
                                                 const _Float16* __restrict__ expem,
                                                 const float* __restrict__ trans,
                                                 const float* __restrict__ start_trans,
                                                 const float* __restrict__ end_trans,
                                                 float* __restrict__ denom) {
  __shared__ float tmp[4 * 68 + 4];
  const int lane = threadIdx.x;
  const int n16 = lane & 15, quad = lane >> 4;
  const int b = n16 & 3;
  const int gb = blockIdx.x * 4 + b;

  half8_t ef[4][2];  // exp(trans)*2^-6 in B-frag layout [nt][kf]
#pragma unroll
  for (int nt = 0; nt < 4; ++nt)
#pragma unroll
    for (int kf = 0; kf < 2; ++kf)
#pragma unroll
      for (int i = 0; i < 8; ++i)
        ef[nt][kf][i] =
            (_Float16)(fast_exp(trans[(kf * 32 + quad * 8 + i) * NTAG + nt * 16 + n16]) * 0.015625f);

  float sv[16], et[16];
#pragma unroll
  for (int kf = 0; kf < 2; ++kf) {
    const int j0 = kf * 32 + quad * 8;
    float4_t s0 = *(const float4_t*)(start_trans + j0);
    float4_t s1 = *(const float4_t*)(start_trans + j0 + 4);
    float4_t e0 = *(const float4_t*)(end_trans + j0);
    float4_t e1 = *(const float4_t*)(end_trans + j0 + 4);
    float4_t m0v = *(const float4_t*)(em + (size_t)gb * NTAG + j0);
    float4_t m1v = *(const float4_t*)(em + (size_t)gb * NTAG + j0 + 4);
#pragma unroll
    for (int i = 0; i < 4; ++i) {
      sv[kf * 8 + i] = s0[i] + m0v[i];
      sv[kf * 8 + 4 + i] = s1[i] + m1v[i];
      et[kf * 8 + i] = e0[i];
      et[kf * 8 + 4 + i] = e1[i];
    }
  }
  float m0;
  {
    float mx[8];
#pragma unroll
    for (int i = 0; i < 8; ++i) mx[i] = fmaxf(sv[i], sv[8 + i]);
#pragma unroll
    for (int i = 0; i < 4; ++i) mx[i] = fmaxf(mx[i], mx[4 + i]);
    m0 = fmaxf(fmaxf(mx[0], mx[1]), fmaxf(mx[2], mx[3]));
    m0 = fmaxf(m0, __shfl_xor(m0, 16, 64));
    m0 = fmaxf(m0, __shfl_xor(m0, 32, 64));
  }
  half8_t pa[2];  // alpha in A-frag layout, f16
#pragma unroll
  for (int kf = 0; kf < 2; ++kf)
#pragma unroll
    for (int i = 0; i < 8; ++i) pa[kf][i] = (_Float16)fast_exp(sv[kf * 8 + i] - m0);
  float lz2 = 0.f;

  const _Float16* exb = expem + (size_t)gb * NTAG;
  half8_t gn0 = *(const half8_t*)(exb + 8192 + quad * 8);
  half8_t gn1 = *(const half8_t*)(exb + 8192 + 32 + quad * 8);

  for (int t = 1; t < TT; ++t) {
    const half8_t gc0 = gn0, gc1 = gn1;
    if (t + 1 < TT) {
      gn0 = *(const half8_t*)(exb + (size_t)(t + 1) * 8192 + quad * 8);
      gn1 = *(const half8_t*)(exb + (size_t)(t + 1) * 8192 + 32 + quad * 8);
    }
    float4_t a0 = {0.f, 0.f, 0.f, 0.f}, a1 = a0, a2 = a0, a3 = a0;
    a0 = __builtin_amdgcn_mfma_f32_16x16x32_f16(pa[0], ef[0][0], a0, 0, 0, 0);
    a1 = __builtin_amdgcn_mfma_f32_16x16x32_f16(pa[0], ef[1][0], a1, 0, 0, 0);
    a2 = __builtin_amdgcn_mfma_f32_16x16x32_f16(pa[0], ef[2][0], a2, 0, 0, 0);
    a3 = __builtin_amdgcn_mfma_f32_16x16x32_f16(pa[0], ef[3][0], a3, 0, 0, 0);
    a0 = __builtin_amdgcn_mfma_f32_16x16x32_f16(pa[1], ef[0][1], a0, 0, 0, 0);
    a1 = __builtin_amdgcn_mfma_f32_16x16x32_f16(pa[1], ef[1][1], a1, 0, 0, 0);
    a2 = __builtin_amdgcn_mfma_f32_16x16x32_f16(pa[1], ef[2][1], a2, 0, 0, 0);
    a3 = __builtin_amdgcn_mfma_f32_16x16x32_f16(pa[1], ef[3][1], a3, 0, 0, 0);
    // acc[nt][r] = q[b=r][j'=nt*16+n16]; lane writes its quad's nt -> rows r, cols quad*16+n16
    const float4_t aq = (quad == 0) ? a0 : (quad == 1) ? a1 : (quad == 2) ? a2 : a3;
    tmp[0 * 68 + quad * 16 + n16] = aq[0];
    tmp[1 * 68 + quad * 16 + n16] = aq[1];
    tmp[2 * 68 + quad * 16 + n16] = aq[2];
    tmp[3 * 68 + quad * 16 + n16] = aq[3];
    lds_fence();
    const float4_t v0 = *(const float4_t*)(&tmp[b * 68 + quad * 8]);
    const float4_t v1 = *(const float4_t*)(&tmp[b * 68 + quad * 8 + 4]);
    const float4_t v2 = *(const float4_t*)(&tmp[b * 68 + 32 + quad * 8]);
    const float4_t v3 = *(const float4_t*)(&tmp[b * 68 + 32 + quad * 8 + 4]);
    half2_t* p0 = (half2_t*)&pa[0];
    half2_t* p1 = (half2_t*)&pa[1];
    const half2_t* g0 = (const half2_t*)&gc0;
    const half2_t* g1 = (const half2_t*)&gc1;
    p0[0] = cvt_pk(v0[0], v0[1]) * g0[0];
    p0[1] = cvt_pk(v0[2], v0[3]) * g0[1];
    p0[2] = cvt_pk(v1[0], v1[1]) * g0[2];
    p0[3] = cvt_pk(v1[2], v1[3]) * g0[3];
    p1[0] = cvt_pk(v2[0], v2[1]) * g1[0];
    p1[1] = cvt_pk(v2[2], v2[3]) * g1[1];
    p1[2] = cvt_pk(v3[0], v3[1]) * g1[2];
    p1[3] = cvt_pk(v3[2], v3[3]) * g1[3];
    if ((t & 15) == 0) {  // periodic renorm (drift-bounded between renorms)
      half2_t m2 = __builtin_elementwise_max(p0[0], p0[1]);
      m2 = __builtin_elementwise_max(m2, __builtin_elementwise_max(p0[2], p0[3]));
      m2 = __builtin_elementwise_max(m2, __builtin_elementwise_max(p1[0], p1[1]));
      m2 = __builtin_elementwise_max(m2, __builtin_elementwise_max(p1[2], p1[3]));
      float mm = fmaxf((float)m2[0], (float)m2[1]);
      mm = fmaxf(mm, __shfl_xor(mm, 16, 64));
      mm = fmaxf(mm, __shfl_xor(mm, 32, 64));
      lz2 += __builtin_amdgcn_logf(mm);  // log2
      const half2_t rc = h2bc(__builtin_amdgcn_rcpf(mm));
#pragma unroll
      for (int j = 0; j < 4; ++j) { p0[j] *= rc; p1[j] *= rc; }
    }
  }

  float w = 0.f;
#pragma unroll
  for (int kf = 0; kf < 2; ++kf)
#pragma unroll
    for (int i = 0; i < 8; ++i) w += (float)pa[kf][i] * fast_exp(et[kf * 8 + i]);
  w += __shfl_xor(w, 16, 64);
  w += __shfl_xor(w, 32, 64);
  if (lane < 4)
    denom[blockIdx.x * 4 + lane] =
        m0 + 0.693147180559945f * (lz2 + 6138.0f + __builtin_amdgcn_logf(w));
}

// ---------------------------------------------------------------- numerator
__global__ __launch_bounds__(256) void numer_kernel(const float* __restrict__ em,
                                                    const int* __restrict__ tags,
                                                    const float* __restrict__ trans,
                                                    const float* __restrict__ start_trans,
                                                    const float* __restrict__ end_trans,
                                                    float* __restrict__ num) {
  const int b = blockIdx.x;
  const int tg = tags[b];
  float acc = 0.f;
  for (int t = threadIdx.x; t < TT; t += 256)
    acc += em[((size_t)t * BB + b) * NTAG + tg];
#pragma unroll
  for (int off = 32; off > 0; off >>= 1) acc += __shfl_xor(acc, off, 64);
  __shared__ float red[4];
  if ((threadIdx.x & 63) == 0) red[threadIdx.x >> 6] = acc;
  __syncthreads();
  if (threadIdx.x == 0) {
    const float tot = red[0] + red[1] + red[2] + red[3];
    num[b] = start_trans[tg] + end_trans[tg] + 1023.0f * trans[tg * NTAG + tg] + tot;
  }
}

// ---------------------------------------------------------------- final
__global__ __launch_bounds__(128) void final_kernel(const float* __restrict__ denom,
                                                    const float* __restrict__ num,
                                                    float* __restrict__ out) {
  const int tid = threadIdx.x;
  float v = denom[tid] - num[tid];
#pragma unroll
  for (int off = 32; off > 0; off >>= 1) v += __shfl_xor(v, off, 64);
  __shared__ float red[2];
  if ((tid & 63) == 0) red[tid >> 6] = v;
  __syncthreads();
  if (tid == 0) out[0] = red[0] + red[1];
}

extern "C" void kernel_launch(void* const* d_in, const int* in_sizes, int n_in,
                              void* d_out, int out_size, void* d_ws, size_t ws_size,
                              hipStream_t stream) {
  const int* kmers = (const int*)d_in[0];
  const int* tags = (const int*)d_in[1];
  const float* emb = (const float*)d_in[2];
  const float* w_ih_f = (const float*)d_in[3];
  const float* w_hh_f = (const float*)d_in[4];
  const float* b_ih_f = (const float*)d_in[5];
  const float* b_hh_f = (const float*)d_in[6];
  const float* w_ih_b = (const float*)d_in[7];
  const float* w_hh_b = (const float*)d_in[8];
  const float* b_ih_b = (const float*)d_in[9];
  const float* b_hh_b = (const float*)d_in[10];
  const float* w_proj = (const float*)d_in[11];
  const float* b_proj = (const float*)d_in[12];
  const float* start_trans = (const float*)d_in[13];
  const float* end_trans = (const float*)d_in[14];
  const float* trans = (const float*)d_in[15];

  int nseg;
  if (ws_size >= 235078656ull) nseg = 2;
  else if (ws_size >= 167969792ull) nseg = 4;
  else if (ws_size >= 134415360ull) nseg = 8;
  else nseg = 16;
  const int Tseg = TT / nseg;
  const size_t xg_bytes = 268435456ull / (size_t)nseg;

  char* ws = (char*)d_ws;
  half4_t* x = (half4_t*)ws;                       // [0, 33.5M); em aliases after xg done
  _Float16* h_cat = (_Float16*)(ws + 33554432);    // [33.5M, 100.7M)
  _Float16* xgbuf = (_Float16*)(ws + 100663296);   // [100.7M, +xg_bytes)
  _Float16* expem = (_Float16*)(ws + 100663296);   // 16.8M, aliases xgbuf (dead after lstm)
  _Float16* h_state = (_Float16*)(ws + 100663296 + xg_bytes);    // 65,536 B
  float* c_state = (float*)(ws + 100663296 + xg_bytes + 65536);  // 131,072 B
  float* denom = (float*)(ws + 100663296 + xg_bytes + 196608);   // 512 B
  float* num = denom + 128;
  float* em = (float*)ws;
  float* out = (float*)d_out;

  hipLaunchKernelGGL(init_kernel, dim3(48), dim3(256), 0, stream, (float4_t*)h_state);
  hipLaunchKernelGGL(embed_kernel, dim3(16384), dim3(256), 0, stream, kmers, emb, x);
  for (int s = 0; s < nseg; ++s) {
    hipLaunchKernelGGL(xg_kernel, dim3(Tseg), dim3(1024), 0, stream, (const _Float16*)x,
                       w_ih_f, b_ih_f, b_hh_f, w_ih_b, b_ih_b, b_hh_b, xgbuf, s, Tseg);
    hipLaunchKernelGGL(lstm_kernel, dim3(16), dim3(512), 0, stream, (const _Float16*)xgbuf,
                       w_hh_f, w_hh_b, h_cat, h_state, c_state, s, Tseg);
  }
  hipLaunchKernelGGL(emis_kernel, dim3(2048), dim3(256), 0, stream, h_cat, w_proj, b_proj, em,
                     expem);
  hipLaunchKernelGGL(crf_kernel, dim3(32), dim3(64), 0, stream, em, (const _Float16*)expem,
                     trans, start_trans, end_trans, denom);
  hipLaunchKernelGGL(numer_kernel, dim3(128), dim3(256), 0, stream, em, tags, trans, start_trans,
                     end_trans, num);
  hipLaunchKernelGGL(final_kernel, dim3(1), dim3(128), 0, stream, denom, num, out);
}